// Round 1
// baseline (140.163 us; speedup 1.0000x reference)
//
#include <hip/hip_runtime.h>

// GaitPINN: encoder MLP -> 2-D neural ODE (tanh MLP vector field) -> decoder.
// Strategy: fixed-step RK4 (85 segments) + cubic Hermite dense output at
// theta=1/3,2/3 replaces adaptive dopri5 (error ~1e-4 << 7.9e-2 threshold).
// 4 lanes per sample (8 of 32 hidden units each, quad shfl_xor butterfly)
// -> 65536 threads = 1024 waves = all 1024 SIMDs occupied.

constexpr int   BATCH = 16384;
constexpr int   NSEG  = 85;
constexpr float DT    = 1.0f / (float)NSEG;
constexpr float DT2   = DT * 0.5f;
constexpr float DT6   = DT / 6.0f;
constexpr float SCALE = 2.8853900817779268f; // 2*log2(e): tanh(s)=1-2/(1+exp2(SCALE*s))

// Cubic Hermite basis at theta=1/3 and 2/3, dt folded into tangent terms
constexpr float A00 = 20.f/27.f, A01 = 7.f/27.f,  A10 = (4.f/27.f)*DT,  A11 = (-2.f/27.f)*DT;
constexpr float B00 = 7.f/27.f,  B01 = 20.f/27.f, B10 = (2.f/27.f)*DT,  B11 = (-4.f/27.f)*DT;

__device__ __forceinline__ float fast_exp2(float x) {
#if __has_builtin(__builtin_amdgcn_exp2f)
  return __builtin_amdgcn_exp2f(x);
#else
  return exp2f(x);
#endif
}

__device__ __forceinline__ float fast_rcp(float x) {
#if __has_builtin(__builtin_amdgcn_rcpf)
  return __builtin_amdgcn_rcpf(x);
#else
  return 1.0f / x;
#endif
}

__global__ __launch_bounds__(256) void gait_kernel(
    const float* __restrict__ x,
    const float* __restrict__ We1, const float* __restrict__ be1,
    const float* __restrict__ We2, const float* __restrict__ be2,
    const float* __restrict__ We3, const float* __restrict__ be3,
    const float* __restrict__ Wo1, const float* __restrict__ bo1,
    const float* __restrict__ Wo2, const float* __restrict__ bo2,
    const float* __restrict__ Wd,  const float* __restrict__ bd,
    float* __restrict__ out)
{
  const int t   = blockIdx.x * 256 + threadIdx.x;
  const int b   = t >> 2;   // sample id
  const int sub = t & 3;    // lane within the sample's quad

  // ---------------- encoder (redundant on all 4 lanes; issue-bound so free) ----
  const float* xb = x + (size_t)b * 2304;  // x[b, 0, :], row stride 256*9
  float xv[9];
#pragma unroll
  for (int i = 0; i < 9; ++i) xv[i] = xb[i];

  float h1[64];
#pragma unroll
  for (int j = 0; j < 64; ++j) {
    float s = be1[j];
#pragma unroll
    for (int i = 0; i < 9; ++i) s = fmaf(xv[i], We1[i*64 + j], s);
    h1[j] = fmaxf(s, 0.0f);
  }

  float z0a = be3[0], z0b = be3[1];
#pragma unroll 8
  for (int j = 0; j < 64; ++j) {
    float s = be2[j];
#pragma unroll
    for (int i = 0; i < 64; ++i) s = fmaf(h1[i], We2[i*64 + j], s);
    s = fmaxf(s, 0.0f);
    z0a = fmaf(s, We3[j*2 + 0], z0a);
    z0b = fmaf(s, We3[j*2 + 1], z0b);
  }

  // write z0 (out[0 .. 32767]); quad-lane 3 owns it
  if (sub == 3) {
    float2 v; v.x = z0a; v.y = z0b;
    *reinterpret_cast<float2*>(out + (size_t)b * 2) = v;
  }

  // decoder weights (broadcast loads, tiny)
  float wd[6], bdv[3];
#pragma unroll
  for (int i = 0; i < 6; ++i) wd[i] = Wd[i];
#pragma unroll
  for (int i = 0; i < 3; ++i) bdv[i] = bd[i];

  // this lane's 8-wide slice of the 32 hidden units of the vector field
  float w1a[8], w1b[8], b1s[8], w2a[8], w2b[8];
  const int j0 = sub * 8;
#pragma unroll
  for (int q = 0; q < 8; ++q) {
    w1a[q] = Wo1[      j0 + q] * SCALE;   // Wo1[0][j]
    w1b[q] = Wo1[32 +  j0 + q] * SCALE;   // Wo1[1][j]
    b1s[q] = bo1[      j0 + q] * SCALE;
    w2a[q] = Wo2[(j0 + q)*2 + 0];
    w2b[q] = Wo2[(j0 + q)*2 + 1];
  }
  const float b20 = bo2[0], b21 = bo2[1];

  float* __restrict__ zt = out + 32768;             // z_traj (256,16384,2)
  float* __restrict__ xh = out + 32768 + 8388608;   // x_hat  (256,16384,3)

  // vf(z) = tanh(z@Wo1+bo1)@Wo2+bo2, split over the quad, butterfly-reduced.
  // All 4 lanes end with bitwise-identical (o0,o1) -> replicated state stays synced.
  auto vf = [&](float za, float zb, float& o0, float& o1) {
    float a0 = 0.f, a1 = 0.f;
#pragma unroll
    for (int q = 0; q < 8; ++q) {
      float u  = fmaf(za, w1a[q], fmaf(zb, w1b[q], b1s[q]));
      float e  = fast_exp2(u);
      float r  = fast_rcp(e + 1.0f);
      float th = fmaf(-2.0f, r, 1.0f);      // tanh
      a0 = fmaf(th, w2a[q], a0);
      a1 = fmaf(th, w2b[q], a1);
    }
    a0 += __shfl_xor(a0, 1); a0 += __shfl_xor(a0, 2);
    a1 += __shfl_xor(a1, 1); a1 += __shfl_xor(a1, 2);
    o0 = a0 + b20; o1 = a1 + b21;
  };

  // emit output time index m given interpolated state (za,zb); store roles by quad lane
  auto emit = [&](int m, float za, float zb) {
    if (sub == 0) {
      float2 v; v.x = za; v.y = zb;
      *reinterpret_cast<float2*>(zt + (size_t)m * (BATCH*2) + b*2) = v;
    } else if (sub == 1) {
      float* p = xh + (size_t)m * (BATCH*3) + b*3;  // only 4B-aligned: scalar stores
      p[0] = fmaf(za, wd[0], fmaf(zb, wd[3], bdv[0]));
      p[1] = fmaf(za, wd[1], fmaf(zb, wd[4], bdv[1]));
    } else if (sub == 2) {
      xh[(size_t)m * (BATCH*3) + b*3 + 2] = fmaf(za, wd[2], fmaf(zb, wd[5], bdv[2]));
    }
  };

  float za = z0a, zb = z0b;
  float fa, fb;
  vf(za, zb, fa, fb);        // k1 of first segment (carried across segments)
  emit(0, za, zb);

  for (int k = 0; k < NSEG; ++k) {
    float k2a, k2b, k3a, k3b, k4a, k4b, fna, fnb;
    vf(fmaf(DT2, fa,  za), fmaf(DT2, fb,  zb), k2a, k2b);
    vf(fmaf(DT2, k2a, za), fmaf(DT2, k2b, zb), k3a, k3b);
    vf(fmaf(DT,  k3a, za), fmaf(DT,  k3b, zb), k4a, k4b);
    float zna = fmaf(DT6, fa + k4a + 2.0f*(k2a + k3a), za);
    float znb = fmaf(DT6, fb + k4b + 2.0f*(k2b + k3b), zb);
    vf(zna, znb, fna, fnb);  // next segment's k1 + Hermite end-tangent

    emit(3*k + 1, A00*za + A01*zna + A10*fa + A11*fna,
                  A00*zb + A01*znb + A10*fb + A11*fnb);
    emit(3*k + 2, B00*za + B01*zna + B10*fa + B11*fna,
                  B00*zb + B01*znb + B10*fb + B11*fnb);
    emit(3*k + 3, zna, znb);  // exact node; k=84 -> m=255 (t=1)

    za = zna; zb = znb; fa = fna; fb = fnb;
  }
}

extern "C" void kernel_launch(void* const* d_in, const int* in_sizes, int n_in,
                              void* d_out, int out_size, void* d_ws, size_t ws_size,
                              hipStream_t stream)
{
  const float* x   = (const float*)d_in[0];
  const float* We1 = (const float*)d_in[1];
  const float* be1 = (const float*)d_in[2];
  const float* We2 = (const float*)d_in[3];
  const float* be2 = (const float*)d_in[4];
  const float* We3 = (const float*)d_in[5];
  const float* be3 = (const float*)d_in[6];
  const float* Wo1 = (const float*)d_in[7];
  const float* bo1 = (const float*)d_in[8];
  const float* Wo2 = (const float*)d_in[9];
  const float* bo2 = (const float*)d_in[10];
  const float* Wd  = (const float*)d_in[11];
  const float* bd  = (const float*)d_in[12];

  dim3 grid(BATCH * 4 / 256), block(256);
  gait_kernel<<<grid, block, 0, stream>>>(x, We1, be1, We2, be2, We3, be3,
                                          Wo1, bo1, Wo2, bo2, Wd, bd,
                                          (float*)d_out);
}

// Round 2
// 119.635 us; speedup vs baseline: 1.1716x; 1.1716x over previous
//
#include <hip/hip_runtime.h>

// GaitPINN: encoder MLP -> 2-D neural ODE (tanh MLP vector field) -> decoder.
// Fixed-step RK4 (85 segments) + cubic Hermite dense output at theta=1/3,2/3
// replaces adaptive dopri5 (absmax 0.016 << 0.079 threshold, measured R1).
// R2 change: 8 lanes per sample (4 of 32 hidden units each) -> 131072 threads
// = 2048 waves = 2 waves/SIMD (was 1), with the 8-lane allreduce done entirely
// in full-rate DPP (quad xor1, quad xor2, row_half_mirror) - no LDS pipe.

constexpr int   BATCH = 16384;
constexpr int   NSEG  = 85;
constexpr float DT    = 1.0f / (float)NSEG;
constexpr float DT2   = DT * 0.5f;
constexpr float DT6   = DT / 6.0f;
constexpr float SCALE = 2.8853900817779268f; // 2*log2(e): tanh(s)=1-2/(1+exp2(SCALE*s))

// Cubic Hermite basis at theta=1/3 and 2/3, dt folded into tangent terms
constexpr float A00 = 20.f/27.f, A01 = 7.f/27.f,  A10 = (4.f/27.f)*DT,  A11 = (-2.f/27.f)*DT;
constexpr float B00 = 7.f/27.f,  B01 = 20.f/27.f, B10 = (2.f/27.f)*DT,  B11 = (-4.f/27.f)*DT;

__device__ __forceinline__ float fast_exp2(float x) {
#if __has_builtin(__builtin_amdgcn_exp2f)
  return __builtin_amdgcn_exp2f(x);
#else
  return exp2f(x);
#endif
}

__device__ __forceinline__ float fast_rcp(float x) {
#if __has_builtin(__builtin_amdgcn_rcpf)
  return __builtin_amdgcn_rcpf(x);
#else
  return 1.0f / x;
#endif
}

// v += lane-permuted v, permutation given by DPP ctrl. Full-rate VALU.
template<int CTRL>
__device__ __forceinline__ float dpp_add(float v) {
  int sw = __builtin_amdgcn_update_dpp(0, __float_as_int(v), CTRL, 0xF, 0xF, true);
  return v + __int_as_float(sw);
}

// Butterfly allreduce over each aligned 8-lane group. Steps: xor1 (quad_perm
// {1,0,3,2}=0xB1), xor2 (quad_perm {2,3,0,1}=0x4E), then row_half_mirror
// (0x141, lane i <-> 7-i within the 8-group; valid 3rd step because lanes 0-3
// and 4-7 each hold their half-sum). Every step adds the same commutative
// pair on both partners -> all 8 lanes end bitwise identical.
__device__ __forceinline__ float allred8(float v) {
  v = dpp_add<0xB1>(v);
  v = dpp_add<0x4E>(v);
  v = dpp_add<0x141>(v);
  return v;
}

__global__ __launch_bounds__(256) void gait_kernel(
    const float* __restrict__ x,
    const float* __restrict__ We1, const float* __restrict__ be1,
    const float* __restrict__ We2, const float* __restrict__ be2,
    const float* __restrict__ We3, const float* __restrict__ be3,
    const float* __restrict__ Wo1, const float* __restrict__ bo1,
    const float* __restrict__ Wo2, const float* __restrict__ bo2,
    const float* __restrict__ Wd,  const float* __restrict__ bd,
    float* __restrict__ out)
{
  const int t   = blockIdx.x * 256 + threadIdx.x;
  const int b   = t >> 3;   // sample id
  const int sub = t & 7;    // lane within the sample's 8-lane group

  // ---------------- encoder ----------------
  // Layer 1 (9->64): redundant on all 8 lanes (cheap, keeps h1 lane-local).
  const float* xb = x + (size_t)b * 2304;  // x[b, 0, :], row stride 256*9
  float xv[9];
#pragma unroll
  for (int i = 0; i < 9; ++i) xv[i] = xb[i];

  float h1[64];
#pragma unroll
  for (int j = 0; j < 64; ++j) {
    float s = be1[j];
#pragma unroll
    for (int i = 0; i < 9; ++i) s = fmaf(xv[i], We1[i*64 + j], s);
    h1[j] = fmaxf(s, 0.0f);
  }

  // Layer 2+3 (64->64->2): split the 64 columns across the 8 lanes (8 each),
  // accumulate partial z0, DPP-allreduce -> all lanes get identical z0.
  const int c0 = sub * 8;
  float z0a = 0.f, z0b = 0.f;
#pragma unroll 2
  for (int jj = 0; jj < 8; ++jj) {
    const int j = c0 + jj;
    float s = be2[j];
#pragma unroll
    for (int i = 0; i < 64; ++i) s = fmaf(h1[i], We2[i*64 + j], s);
    s = fmaxf(s, 0.0f);
    z0a = fmaf(s, We3[j*2 + 0], z0a);
    z0b = fmaf(s, We3[j*2 + 1], z0b);
  }
  z0a = allred8(z0a) + be3[0];
  z0b = allred8(z0b) + be3[1];

  // write z0 (out[0 .. 32767]); one lane per sample owns it
  if (sub == 3) {
    float2 v; v.x = z0a; v.y = z0b;
    *reinterpret_cast<float2*>(out + (size_t)b * 2) = v;
  }

  // decoder weights (broadcast loads, tiny)
  float wd[6], bdv[3];
#pragma unroll
  for (int i = 0; i < 6; ++i) wd[i] = Wd[i];
#pragma unroll
  for (int i = 0; i < 3; ++i) bdv[i] = bd[i];

  // this lane's 4-wide slice of the 32 hidden units of the vector field
  float w1a[4], w1b[4], b1s[4], w2a[4], w2b[4];
  const int u0 = sub * 4;
#pragma unroll
  for (int q = 0; q < 4; ++q) {
    w1a[q] = Wo1[      u0 + q] * SCALE;   // Wo1[0][u]
    w1b[q] = Wo1[32 +  u0 + q] * SCALE;   // Wo1[1][u]
    b1s[q] = bo1[      u0 + q] * SCALE;
    w2a[q] = Wo2[(u0 + q)*2 + 0];
    w2b[q] = Wo2[(u0 + q)*2 + 1];
  }
  const float b20 = bo2[0], b21 = bo2[1];

  float* __restrict__ zt = out + 32768;             // z_traj (256,16384,2)
  float* __restrict__ xh = out + 32768 + 8388608;   // x_hat  (256,16384,3)

  // vf(z) = tanh(z@Wo1+bo1)@Wo2+bo2, split over 8 lanes, DPP-allreduced.
  // All 8 lanes end with bitwise-identical (o0,o1) -> replicated state synced.
  auto vf = [&](float za, float zb, float& o0, float& o1) {
    float a0 = 0.f, a1 = 0.f;
#pragma unroll
    for (int q = 0; q < 4; ++q) {
      float u  = fmaf(za, w1a[q], fmaf(zb, w1b[q], b1s[q]));
      float e  = fast_exp2(u);
      float r  = fast_rcp(e + 1.0f);
      float th = fmaf(-2.0f, r, 1.0f);      // tanh
      a0 = fmaf(th, w2a[q], a0);
      a1 = fmaf(th, w2b[q], a1);
    }
    o0 = allred8(a0) + b20;
    o1 = allred8(a1) + b21;
  };

  // emit output time index m given interpolated state (za,zb); roles by lane
  auto emit = [&](int m, float za, float zb) {
    if (sub == 0) {
      float2 v; v.x = za; v.y = zb;
      *reinterpret_cast<float2*>(zt + (size_t)m * (BATCH*2) + b*2) = v;
    } else if (sub == 1) {
      float* p = xh + (size_t)m * (BATCH*3) + b*3;  // only 4B-aligned: scalar stores
      p[0] = fmaf(za, wd[0], fmaf(zb, wd[3], bdv[0]));
      p[1] = fmaf(za, wd[1], fmaf(zb, wd[4], bdv[1]));
    } else if (sub == 2) {
      xh[(size_t)m * (BATCH*3) + b*3 + 2] = fmaf(za, wd[2], fmaf(zb, wd[5], bdv[2]));
    }
  };

  float za = z0a, zb = z0b;
  float fa, fb;
  vf(za, zb, fa, fb);        // k1 of first segment (carried across segments)
  emit(0, za, zb);

  for (int k = 0; k < NSEG; ++k) {
    float k2a, k2b, k3a, k3b, k4a, k4b, fna, fnb;
    vf(fmaf(DT2, fa,  za), fmaf(DT2, fb,  zb), k2a, k2b);
    vf(fmaf(DT2, k2a, za), fmaf(DT2, k2b, zb), k3a, k3b);
    vf(fmaf(DT,  k3a, za), fmaf(DT,  k3b, zb), k4a, k4b);
    float zna = fmaf(DT6, fa + k4a + 2.0f*(k2a + k3a), za);
    float znb = fmaf(DT6, fb + k4b + 2.0f*(k2b + k3b), zb);
    vf(zna, znb, fna, fnb);  // next segment's k1 + Hermite end-tangent

    emit(3*k + 1, A00*za + A01*zna + A10*fa + A11*fna,
                  A00*zb + A01*znb + A10*fb + A11*fnb);
    emit(3*k + 2, B00*za + B01*zna + B10*fa + B11*fna,
                  B00*zb + B01*znb + B10*fb + B11*fnb);
    emit(3*k + 3, zna, znb);  // exact node; k=84 -> m=255 (t=1)

    za = zna; zb = znb; fa = fna; fb = fnb;
  }
}

extern "C" void kernel_launch(void* const* d_in, const int* in_sizes, int n_in,
                              void* d_out, int out_size, void* d_ws, size_t ws_size,
                              hipStream_t stream)
{
  const float* x   = (const float*)d_in[0];
  const float* We1 = (const float*)d_in[1];
  const float* be1 = (const float*)d_in[2];
  const float* We2 = (const float*)d_in[3];
  const float* be2 = (const float*)d_in[4];
  const float* We3 = (const float*)d_in[5];
  const float* be3 = (const float*)d_in[6];
  const float* Wo1 = (const float*)d_in[7];
  const float* bo1 = (const float*)d_in[8];
  const float* Wo2 = (const float*)d_in[9];
  const float* bo2 = (const float*)d_in[10];
  const float* Wd  = (const float*)d_in[11];
  const float* bd  = (const float*)d_in[12];

  dim3 grid(BATCH * 8 / 256), block(256);
  gait_kernel<<<grid, block, 0, stream>>>(x, We1, be1, We2, be2, We3, be3,
                                          Wo1, bo1, Wo2, bo2, Wd, bd,
                                          (float*)d_out);
}